// Round 2
// baseline (10729.720 us; speedup 1.0000x reference)
//
#include <hip/hip_runtime.h>
#include <hip/hip_bf16.h>

// Problem constants (fp32 problem: b=2, s=2048, D=2048, 32 q-heads / 8 kv-groups, d=64)
#define TOKENS   4096      // b*s
#define SEQ      2048
#define DMODEL   2048
#define CONCAT   3072      // 32*64 + 8*(64+64)
#define NHEADS   32
#define NGROUPS  8
#define HPERG    4
#define CQ       2048      // NHEADS*DQK
#define CK       512       // NGROUPS*DQK

// ---------------- RMSNorm: one block (256 thr) per token ----------------
__global__ void rmsnorm_kernel(const float* __restrict__ x,
                               const float* __restrict__ w,
                               float* __restrict__ y) {
    int t = blockIdx.x;
    const float4* xr = (const float4*)(x + (size_t)t * DMODEL);
    float4 v[2];
    float ss = 0.f;
#pragma unroll
    for (int i = 0; i < 2; i++) {
        v[i] = xr[threadIdx.x + i * 256];
        ss += v[i].x * v[i].x + v[i].y * v[i].y + v[i].z * v[i].z + v[i].w * v[i].w;
    }
#pragma unroll
    for (int off = 32; off >= 1; off >>= 1) ss += __shfl_xor(ss, off);
    __shared__ float red[4];
    int wid = threadIdx.x >> 6;
    if ((threadIdx.x & 63) == 0) red[wid] = ss;
    __syncthreads();
    float total = red[0] + red[1] + red[2] + red[3];
    float scale = rsqrtf(total * (1.0f / DMODEL) + 1e-6f);
    const float4* wr = (const float4*)w;
    float4* yr = (float4*)(y + (size_t)t * DMODEL);
#pragma unroll
    for (int i = 0; i < 2; i++) {
        int c = threadIdx.x + i * 256;
        float4 wv = wr[c];
        float4 o;
        o.x = v[i].x * scale * wv.x;
        o.y = v[i].y * scale * wv.y;
        o.z = v[i].z * scale * wv.z;
        o.w = v[i].w * scale * wv.w;
        yr[c] = o;
    }
}

// ---------------- Tiled GEMM: C[M,N] = A[M,K] * B[N,K]^T (all fp32) ------
// Optional epilogue: OUT = X + C (residual add), fp32.
template <bool EPILOGUE>
__global__ void gemm_tn_kernel(const float* __restrict__ A,
                               const float* __restrict__ B,
                               float* __restrict__ C,
                               const float* __restrict__ X,
                               float* __restrict__ OUT,
                               int M, int N, int K) {
    const int BM = 64, BN = 64, BK = 16;
    __shared__ float As[BK][BM + 1];
    __shared__ float Bs[BK][BN + 1];
    int bm = blockIdx.y * BM, bn = blockIdx.x * BN;
    int tid = threadIdx.x;
    int tx = tid & 15, ty = tid >> 4;
    float acc[4][4] = {};
    int lk = tid & 15;        // k within tile for loads
    int lm = tid >> 4;        // row within tile (stride 16 over 4 passes)
    for (int k0 = 0; k0 < K; k0 += BK) {
#pragma unroll
        for (int i = 0; i < 4; i++) {
            int m = lm + i * 16;
            As[lk][m] = A[(size_t)(bm + m) * K + k0 + lk];
            Bs[lk][m] = B[(size_t)(bn + m) * K + k0 + lk];
        }
        __syncthreads();
#pragma unroll
        for (int k = 0; k < BK; k++) {
            float a[4], b[4];
#pragma unroll
            for (int i = 0; i < 4; i++) a[i] = As[k][ty * 4 + i];
#pragma unroll
            for (int j = 0; j < 4; j++) b[j] = Bs[k][tx * 4 + j];
#pragma unroll
            for (int i = 0; i < 4; i++)
#pragma unroll
                for (int j = 0; j < 4; j++) acc[i][j] += a[i] * b[j];
        }
        __syncthreads();
    }
#pragma unroll
    for (int i = 0; i < 4; i++) {
        int row = bm + ty * 4 + i;
#pragma unroll
        for (int j = 0; j < 4; j++) {
            int col = bn + tx * 4 + j;
            size_t idx = (size_t)row * N + col;
            if (EPILOGUE) {
                OUT[idx] = X[idx] + acc[i][j];
            } else {
                C[idx] = acc[i][j];
            }
        }
    }
}

// ---------------- RoPE in-place on q (heads 0..31) and k (groups 0..7) ---
__global__ void rope_kernel(float* __restrict__ qkv) {
    int t = blockIdx.x;
    int pos = t & (SEQ - 1);
    float* row = qkv + (size_t)t * CONCAT;
    const float LOG2_THETA = 13.287712379549449f; // log2(10000)
    for (int idx = threadIdx.x; idx < 40 * 32; idx += 256) {
        int head = idx >> 5;   // 0..39 (32 q heads then 8 k groups)
        int j = idx & 31;
        float inv = exp2f(-(2.0f * j / 64.0f) * LOG2_THETA);
        float ang = (float)pos * inv;
        float c = cosf(ang), s = sinf(ang);
        int base = (head < 32) ? head * 64 : CQ + (head - 32) * 64;
        float a = row[base + j];
        float b = row[base + 32 + j];
        row[base + j]      = a * c - b * s;
        row[base + 32 + j] = b * c + a * s;
    }
}

// ---------------- Attention: one wave per (b,g,h,sq) query row ----------
__global__ void attn_kernel(const float* __restrict__ qkv,
                            float* __restrict__ o) {
    int gw = blockIdx.x * 4 + (threadIdx.x >> 6);
    int lane = threadIdx.x & 63;
    int sq = gw & (SEQ - 1);
    int rest = gw >> 11;
    int h = rest & 3; rest >>= 2;
    int g = rest & 7;
    int b = rest >> 3;

    const float* base = qkv + (size_t)b * SEQ * CONCAT;
    float q = base[(size_t)sq * CONCAT + (g * HPERG + h) * 64 + lane];
    const float* kcol = base + CQ + g * 64 + lane;
    const float* vcol = base + CQ + CK + g * 64 + lane;

    float m = -1e30f, l = 0.f, acc = 0.f;
    for (int p = 0; p <= sq; p++) {
        float d = q * kcol[(size_t)p * CONCAT];
#pragma unroll
        for (int off = 32; off >= 1; off >>= 1) d += __shfl_xor(d, off);
        float s = d * 0.125f;
        float mn = fmaxf(m, s);
        float alpha = __expf(m - mn);
        float e = __expf(s - mn);
        float vv = vcol[(size_t)p * CONCAT];
        l = l * alpha + e;
        acc = acc * alpha + e * vv;
        m = mn;
    }
    o[((size_t)(b * SEQ + sq)) * DMODEL + (g * HPERG + h) * 64 + lane] = acc / l;
}

extern "C" void kernel_launch(void* const* d_in, const int* in_sizes, int n_in,
                              void* d_out, int out_size, void* d_ws, size_t ws_size,
                              hipStream_t stream) {
    const float* x     = (const float*)d_in[0];
    const float* w_in  = (const float*)d_in[1];
    const float* w_out = (const float*)d_in[2];
    const float* rms_w = (const float*)d_in[3];
    float* out = (float*)d_out;

    // Workspace layout (fp32), o overlaps y (y is dead after GEMM-1):
    //   [0 .. 32MB)   y  (4096x2048)  -> later reused as o (4096x2048)
    //   [32 .. 80MB)  qkv (4096x3072)
    float* y   = (float*)d_ws;
    float* qkv = y + (size_t)TOKENS * DMODEL;
    float* o   = y;   // reuse

    rmsnorm_kernel<<<TOKENS, 256, 0, stream>>>(x, rms_w, y);

    gemm_tn_kernel<false><<<dim3(CONCAT / 64, TOKENS / 64), 256, 0, stream>>>(
        y, w_in, qkv, nullptr, nullptr, TOKENS, CONCAT, DMODEL);

    rope_kernel<<<TOKENS, 256, 0, stream>>>(qkv);

    attn_kernel<<<(TOKENS * NGROUPS * HPERG) / 4, 256, 0, stream>>>(qkv, o);

    gemm_tn_kernel<true><<<dim3(DMODEL / 64, TOKENS / 64), 256, 0, stream>>>(
        o, w_out, nullptr, x, out, TOKENS, DMODEL, DMODEL);
}

// Round 3
// 1956.144 us; speedup vs baseline: 5.4851x; 5.4851x over previous
//
#include <hip/hip_runtime.h>
#include <hip/hip_bf16.h>

// fp32 problem: b=2, s=2048, D=2048, 32 q-heads / 8 kv-groups, d=64
#define TOKENS   4096
#define SEQ      2048
#define DMODEL   2048
#define CONCAT   3072
#define NHEADS   32
#define NGROUPS  8
#define HPERG    4
#define CQ       2048
#define CK       512

typedef __attribute__((ext_vector_type(8))) short bf16x8;
typedef __attribute__((ext_vector_type(4))) float f32x4;

__device__ __forceinline__ ushort f2bf(float f) {
    __hip_bfloat16 h = __float2bfloat16(f);
    return __builtin_bit_cast(ushort, h);
}

// ---------------- RMSNorm: one block (256 thr) per token ----------------
__global__ void rmsnorm_kernel(const float* __restrict__ x,
                               const float* __restrict__ w,
                               float* __restrict__ y) {
    int t = blockIdx.x;
    const float4* xr = (const float4*)(x + (size_t)t * DMODEL);
    float4 v[2];
    float ss = 0.f;
#pragma unroll
    for (int i = 0; i < 2; i++) {
        v[i] = xr[threadIdx.x + i * 256];
        ss += v[i].x * v[i].x + v[i].y * v[i].y + v[i].z * v[i].z + v[i].w * v[i].w;
    }
#pragma unroll
    for (int off = 32; off >= 1; off >>= 1) ss += __shfl_xor(ss, off);
    __shared__ float red[4];
    int wid = threadIdx.x >> 6;
    if ((threadIdx.x & 63) == 0) red[wid] = ss;
    __syncthreads();
    float total = red[0] + red[1] + red[2] + red[3];
    float scale = rsqrtf(total * (1.0f / DMODEL) + 1e-6f);
    const float4* wr = (const float4*)w;
    float4* yr = (float4*)(y + (size_t)t * DMODEL);
#pragma unroll
    for (int i = 0; i < 2; i++) {
        int c = threadIdx.x + i * 256;
        float4 wv = wr[c];
        float4 o;
        o.x = v[i].x * scale * wv.x;
        o.y = v[i].y * scale * wv.y;
        o.z = v[i].z * scale * wv.z;
        o.w = v[i].w * scale * wv.w;
        yr[c] = o;
    }
}

// ---------------- Tiled GEMM: C[M,N] = A[M,K] * B[N,K]^T (fp32) ----------
template <bool EPILOGUE>
__global__ void gemm_tn_kernel(const float* __restrict__ A,
                               const float* __restrict__ B,
                               float* __restrict__ C,
                               const float* __restrict__ X,
                               float* __restrict__ OUT,
                               int M, int N, int K) {
    const int BM = 64, BN = 64, BK = 16;
    __shared__ float As[BK][BM + 1];
    __shared__ float Bs[BK][BN + 1];
    int bm = blockIdx.y * BM, bn = blockIdx.x * BN;
    int tid = threadIdx.x;
    int tx = tid & 15, ty = tid >> 4;
    float acc[4][4] = {};
    int lk = tid & 15;
    int lm = tid >> 4;
    for (int k0 = 0; k0 < K; k0 += BK) {
#pragma unroll
        for (int i = 0; i < 4; i++) {
            int m = lm + i * 16;
            As[lk][m] = A[(size_t)(bm + m) * K + k0 + lk];
            Bs[lk][m] = B[(size_t)(bn + m) * K + k0 + lk];
        }
        __syncthreads();
#pragma unroll
        for (int k = 0; k < BK; k++) {
            float a[4], b[4];
#pragma unroll
            for (int i = 0; i < 4; i++) a[i] = As[k][ty * 4 + i];
#pragma unroll
            for (int j = 0; j < 4; j++) b[j] = Bs[k][tx * 4 + j];
#pragma unroll
            for (int i = 0; i < 4; i++)
#pragma unroll
                for (int j = 0; j < 4; j++) acc[i][j] += a[i] * b[j];
        }
        __syncthreads();
    }
#pragma unroll
    for (int i = 0; i < 4; i++) {
        int row = bm + ty * 4 + i;
#pragma unroll
        for (int j = 0; j < 4; j++) {
            int col = bn + tx * 4 + j;
            size_t idx = (size_t)row * N + col;
            if (EPILOGUE) OUT[idx] = X[idx] + acc[i][j];
            else          C[idx]   = acc[i][j];
        }
    }
}

// ------------- pack_qk: fused RoPE + bf16 cast + per-head layout ---------
// Qb[b][g][h][s][64], Kb[b][g][s][64]
__global__ void pack_qk_kernel(const float* __restrict__ qkv,
                               __hip_bfloat16* __restrict__ Qb,
                               __hip_bfloat16* __restrict__ Kb) {
    int t = blockIdx.x;
    int b = t >> 11, s = t & (SEQ - 1);
    const float* row = qkv + (size_t)t * CONCAT;
    const float LOG2_THETA = 13.287712379549449f;
    for (int i = threadIdx.x; i < CQ + CK; i += 256) {
        int head, d;
        const float* hb;
        if (i < CQ) { head = i >> 6; d = i & 63; hb = row + head * 64; }
        else { head = (i - CQ) >> 6; d = (i - CQ) & 63; hb = row + CQ + head * 64; }
        int j = d & 31;
        float inv = exp2f(-((float)j / 32.0f) * LOG2_THETA);
        float ang = (float)s * inv;
        float c = cosf(ang), sn = sinf(ang);
        float val;
        if (d < 32) val = hb[d] * c - hb[d + 32] * sn;
        else        val = hb[d] * c + hb[d - 32] * sn;
        __hip_bfloat16 bv = __float2bfloat16(val);
        if (i < CQ) {
            int g = head >> 2, h = head & 3;
            Qb[((size_t)((b * 8 + g) * 4 + h) * SEQ + s) * 64 + d] = bv;
        } else {
            Kb[((size_t)(b * 8 + head) * SEQ + s) * 64 + d] = bv;
        }
    }
}

// ------------- pack_v: transpose V to [b][g][d][s] bf16 via LDS ----------
__global__ void pack_v_kernel(const float* __restrict__ qkv,
                              __hip_bfloat16* __restrict__ Vb) {
    int st = blockIdx.x & 31, bg = blockIdx.x >> 5;
    int b = bg >> 3, g = bg & 7;
    __shared__ float tile[64][65];
    int tid = threadIdx.x;
    int ls = tid >> 6;     // 0..3
    int d = tid & 63;
#pragma unroll
    for (int i = 0; i < 16; i++) {
        int s = st * 64 + i * 4 + ls;
        tile[i * 4 + ls][d] = qkv[(size_t)(b * SEQ + s) * CONCAT + CQ + CK + g * 64 + d];
    }
    __syncthreads();
#pragma unroll
    for (int i = 0; i < 16; i++) {
        int drow = i * 4 + ls;
        int scol = tid & 63;
        Vb[((size_t)(bg * 64 + drow)) * SEQ + st * 64 + scol] =
            __float2bfloat16(tile[scol][drow]);
    }
}

// ---------------- MFMA flash attention ----------------------------------
// Block = (b,g,h, 64-query tile); 4 waves x 16 query rows.
// LDS layouts (odd stride 65 -> conflict-free b128 staging & frag reads):
//   Kl[(d>>3)*65 + key]*8 + (d&7)   (K tile, frag order for B-operand of QK^T)
//   Vl[(key>>3)*65 + d]*8 + (key&7) (V tile, frag order for B-operand of PV)
//   Pl[w]: ((key>>3)*16 + q)*8 + (key&7)  (A-operand order for PV)
__global__ __launch_bounds__(256) void attn_mfma_kernel(
        const ushort* __restrict__ Qb, const ushort* __restrict__ Kb,
        const ushort* __restrict__ Vb, float* __restrict__ o) {
    __shared__ __align__(16) ushort Kl[519 * 8];
    __shared__ __align__(16) ushort Vl[519 * 8];
    __shared__ __align__(16) ushort Pl[4][1024];

    int qt = blockIdx.x & 31;
    int bgh = blockIdx.x >> 5;
    int h = bgh & 3, g = (bgh >> 2) & 7, b = bgh >> 5;
    int w = threadIdx.x >> 6, lane = threadIdx.x & 63;
    int n = lane & 15, quad = lane >> 4;
    int qbase = qt * 64;

    const ushort* Qh = Qb + (size_t)((b * 8 + g) * 4 + h) * (SEQ * 64);
    const ushort* Kg0 = Kb + (size_t)(b * 8 + g) * (SEQ * 64);
    const ushort* Vg0 = Vb + (size_t)(b * 8 + g) * (64 * SEQ);

    int qrow = qbase + w * 16 + n;
    bf16x8 aq0 = *(const bf16x8*)(Qh + (size_t)qrow * 64 + quad * 8);
    bf16x8 aq1 = *(const bf16x8*)(Qh + (size_t)qrow * 64 + 32 + quad * 8);

    f32x4 od[4] = {};
    float mrow[4], lrow[4];
#pragma unroll
    for (int r = 0; r < 4; r++) { mrow[r] = -1e30f; lrow[r] = 0.f; }

    ushort* Pw = Pl[w];
    int nkt = qt + 1;
    for (int kt = 0; kt < nkt; kt++) {
        __syncthreads();   // protect K/V LDS from previous iteration's readers
        {
            const ushort* Kg = Kg0 + kt * 64 * 64;
            const ushort* Vg = Vg0 + kt * 64;
#pragma unroll
            for (int rep = 0; rep < 2; rep++) {
                int e = (rep * 256 + threadIdx.x) * 8;
                int key = e >> 6, dblk = (e >> 3) & 7;
                *(bf16x8*)(Kl + (dblk * 65 + key) * 8) = *(const bf16x8*)(Kg + e);
            }
#pragma unroll
            for (int rep = 0; rep < 2; rep++) {
                int e = (rep * 256 + threadIdx.x) * 8;
                int d = e >> 6, kin = e & 63;
                *(bf16x8*)(Vl + ((kin >> 3) * 65 + d) * 8) =
                    *(const bf16x8*)(Vg + (size_t)d * SEQ + kin);
            }
        }
        __syncthreads();

        bool diag = (kt == qt);
        // S = (Q K^T) * scale, causal-masked
        f32x4 s4[4];
#pragma unroll
        for (int t16 = 0; t16 < 4; t16++) {
            if (diag && t16 > w) {
#pragma unroll
                for (int r = 0; r < 4; r++) s4[t16][r] = -1e30f;
                continue;
            }
            bf16x8 bk0 = *(const bf16x8*)(Kl + ((quad) * 65 + t16 * 16 + n) * 8);
            bf16x8 bk1 = *(const bf16x8*)(Kl + ((4 + quad) * 65 + t16 * 16 + n) * 8);
            f32x4 c = {};
            c = __builtin_amdgcn_mfma_f32_16x16x32_bf16(aq0, bk0, c, 0, 0, 0);
            c = __builtin_amdgcn_mfma_f32_16x16x32_bf16(aq1, bk1, c, 0, 0, 0);
#pragma unroll
            for (int r = 0; r < 4; r++) {
                float sv = c[r] * 0.125f;
                if (diag && t16 == w) {
                    int keyr = t16 * 16 + n;
                    int qr = w * 16 + quad * 4 + r;
                    if (keyr > qr) sv = -1e30f;
                }
                s4[t16][r] = sv;
            }
        }

        // online softmax over this 64-key tile (rows = quad*4+r)
        float rmax[4], alpha[4], rsum[4];
#pragma unroll
        for (int r = 0; r < 4; r++)
            rmax[r] = fmaxf(fmaxf(s4[0][r], s4[1][r]), fmaxf(s4[2][r], s4[3][r]));
#pragma unroll
        for (int off = 1; off < 16; off <<= 1)
#pragma unroll
            for (int r = 0; r < 4; r++)
                rmax[r] = fmaxf(rmax[r], __shfl_xor(rmax[r], off));
#pragma unroll
        for (int r = 0; r < 4; r++) {
            float mn = fmaxf(mrow[r], rmax[r]);
            alpha[r] = __expf(mrow[r] - mn);
            mrow[r] = mn;
            rsum[r] = 0.f;
        }
#pragma unroll
        for (int t16 = 0; t16 < 4; t16++)
#pragma unroll
            for (int r = 0; r < 4; r++) {
                float p = __expf(s4[t16][r] - mrow[r]);
                rsum[r] += p;
                int key = t16 * 16 + n;
                Pw[((key >> 3) * 16 + quad * 4 + r) * 8 + (key & 7)] = f2bf(p);
            }
#pragma unroll
        for (int off = 1; off < 16; off <<= 1)
#pragma unroll
            for (int r = 0; r < 4; r++) rsum[r] += __shfl_xor(rsum[r], off);
#pragma unroll
        for (int r = 0; r < 4; r++) lrow[r] = lrow[r] * alpha[r] + rsum[r];
#pragma unroll
        for (int dt = 0; dt < 4; dt++)
#pragma unroll
            for (int r = 0; r < 4; r++) od[dt][r] *= alpha[r];

        // O += P V
#pragma unroll
        for (int kb = 0; kb < 2; kb++) {
            bf16x8 ap = *(const bf16x8*)(Pw + ((kb * 4 + quad) * 16 + n) * 8);
#pragma unroll
            for (int dt = 0; dt < 4; dt++) {
                bf16x8 bv = *(const bf16x8*)(Vl + ((kb * 4 + quad) * 65 + dt * 16 + n) * 8);
                od[dt] = __builtin_amdgcn_mfma_f32_16x16x32_bf16(ap, bv, od[dt], 0, 0, 0);
            }
        }
    }

    // epilogue: O/l -> o[token][head*64+d]  (fp32)
#pragma unroll
    for (int dt = 0; dt < 4; dt++)
#pragma unroll
        for (int r = 0; r < 4; r++) {
            int q = qbase + w * 16 + quad * 4 + r;
            int col = (g * 4 + h) * 64 + dt * 16 + n;
            o[(size_t)(b * SEQ + q) * DMODEL + col] = od[dt][r] / lrow[r];
        }
}

extern "C" void kernel_launch(void* const* d_in, const int* in_sizes, int n_in,
                              void* d_out, int out_size, void* d_ws, size_t ws_size,
                              hipStream_t stream) {
    const float* x     = (const float*)d_in[0];
    const float* w_in  = (const float*)d_in[1];
    const float* w_out = (const float*)d_in[2];
    const float* rms_w = (const float*)d_in[3];
    float* out = (float*)d_out;

    // Workspace (80 MB):
    //   region0 @0   (32MB): y (fp32, dead after GEMM-in) -> Qb(16MB)+Kb(4MB)+Vb(4MB)
    //   region1 @32MB(48MB): qkv (fp32, dead after pack)  -> o (fp32, 32MB)
    float* y = (float*)d_ws;
    __hip_bfloat16* Qb = (__hip_bfloat16*)d_ws;
    __hip_bfloat16* Kb = Qb + (size_t)2 * NGROUPS * HPERG * SEQ * 64;  // +16MB
    __hip_bfloat16* Vb = Kb + (size_t)2 * NGROUPS * SEQ * 64;          // +4MB
    float* qkv = (float*)d_ws + (size_t)TOKENS * DMODEL;
    float* o = qkv;

    rmsnorm_kernel<<<TOKENS, 256, 0, stream>>>(x, rms_w, y);

    gemm_tn_kernel<false><<<dim3(CONCAT / 64, TOKENS / 64), 256, 0, stream>>>(
        y, w_in, qkv, nullptr, nullptr, TOKENS, CONCAT, DMODEL);

    pack_qk_kernel<<<TOKENS, 256, 0, stream>>>(qkv, Qb, Kb);
    pack_v_kernel<<<512, 256, 0, stream>>>(qkv, Vb);

    attn_mfma_kernel<<<2048, 256, 0, stream>>>(
        (const ushort*)Qb, (const ushort*)Kb, (const ushort*)Vb, o);

    gemm_tn_kernel<true><<<dim3(DMODEL / 64, TOKENS / 64), 256, 0, stream>>>(
        o, w_out, nullptr, x, out, TOKENS, DMODEL, DMODEL);
}

// Round 4
// 483.047 us; speedup vs baseline: 22.2126x; 4.0496x over previous
//
#include <hip/hip_runtime.h>
#include <hip/hip_bf16.h>

// fp32 problem: b=2, s=2048, D=2048, 32 q-heads / 8 kv-groups, d=64
#define TOKENS   4096
#define SEQ      2048
#define DMODEL   2048
#define CONCAT   3072
#define NHEADS   32
#define NGROUPS  8
#define HPERG    4
#define CQ       2048
#define CK       512

typedef __attribute__((ext_vector_type(8))) short bf16x8;
typedef __attribute__((ext_vector_type(4))) float f32x4;

__device__ __forceinline__ ushort f2bf(float f) {
    __hip_bfloat16 h = __float2bfloat16(f);
    return __builtin_bit_cast(ushort, h);
}

#define GLOBAL_TO_LDS16(g, l)                                                  \
    __builtin_amdgcn_global_load_lds(                                          \
        (const __attribute__((address_space(1))) void*)(g),                    \
        (__attribute__((address_space(3))) void*)(l), 16, 0, 0)

// ---------------- RMSNorm: one block (256 thr) per token, bf16 out -------
__global__ void rmsnorm_kernel(const float* __restrict__ x,
                               const float* __restrict__ w,
                               ushort* __restrict__ y_bf) {
    int t = blockIdx.x;
    const float4* xr = (const float4*)(x + (size_t)t * DMODEL);
    float4 v[2];
    float ss = 0.f;
#pragma unroll
    for (int i = 0; i < 2; i++) {
        v[i] = xr[threadIdx.x + i * 256];
        ss += v[i].x * v[i].x + v[i].y * v[i].y + v[i].z * v[i].z + v[i].w * v[i].w;
    }
#pragma unroll
    for (int off = 32; off >= 1; off >>= 1) ss += __shfl_xor(ss, off);
    __shared__ float red[4];
    int wid = threadIdx.x >> 6;
    if ((threadIdx.x & 63) == 0) red[wid] = ss;
    __syncthreads();
    float total = red[0] + red[1] + red[2] + red[3];
    float scale = rsqrtf(total * (1.0f / DMODEL) + 1e-6f);
    const float4* wr = (const float4*)w;
    ushort4* yr = (ushort4*)(y_bf + (size_t)t * DMODEL);
#pragma unroll
    for (int i = 0; i < 2; i++) {
        int c = threadIdx.x + i * 256;
        float4 wv = wr[c];
        ushort4 o;
        o.x = f2bf(v[i].x * scale * wv.x);
        o.y = f2bf(v[i].y * scale * wv.y);
        o.z = f2bf(v[i].z * scale * wv.z);
        o.w = f2bf(v[i].w * scale * wv.w);
        yr[c] = o;
    }
}

// ---------------- fp32 -> bf16 cast (weights) ----------------------------
__global__ void pack_bf16_kernel(const float* __restrict__ src,
                                 ushort* __restrict__ dst, int n4) {
    int i = blockIdx.x * 256 + threadIdx.x;
    if (i < n4) {
        float4 v = ((const float4*)src)[i];
        ushort4 o;
        o.x = f2bf(v.x); o.y = f2bf(v.y); o.z = f2bf(v.z); o.w = f2bf(v.w);
        ((ushort4*)dst)[i] = o;
    }
}

// ---------------- MFMA GEMM: C[M,N] = A[M,K] * B[N,K]^T (bf16 in) --------
// m97 structure: 128x128 tile, BK=64, 4 waves, global_load_lds width=16.
// LDS swizzle: tile element (row, kblk) lives at off16 = row*8 + (kblk ^ (row&7));
// staging lane l of group-base rbase fetches global kblk = (l&7)^(l>>3) so the
// DMA's forced "uniform base + lane*16" placement realizes exactly that layout.
// Frag ds_read_b128 then lands 2 lanes/bank (free, m136).
template <bool EPILOGUE>
__global__ __launch_bounds__(256) void gemm_nt_mfma(
        const ushort* __restrict__ A, const ushort* __restrict__ B,
        float* __restrict__ C, const float* __restrict__ X,
        float* __restrict__ OUT, int M, int N, int K) {
    __shared__ __align__(16) ushort As[128 * 64];
    __shared__ __align__(16) ushort Bs[128 * 64];

    const int bm = blockIdx.y * 128, bn = blockIdx.x * 128;
    const int w = threadIdx.x >> 6, lane = threadIdx.x & 63;
    const int n = lane & 15, quad = lane >> 4;
    const int wr = (w & 1) * 64, wc = (w >> 1) * 64;

    const int r8 = lane >> 3;            // row within the 8-row staging group
    const int kb = (lane & 7) ^ r8;      // swizzled k-block this lane fetches

    f32x4 acc[4][4] = {};

    for (int k0 = 0; k0 < K; k0 += 64) {
        __syncthreads();                 // previous tile's readers done
#pragma unroll
        for (int i = 0; i < 4; i++) {
            int rbase = (w * 4 + i) * 8;
            const ushort* ga = A + (size_t)(bm + rbase + r8) * K + k0 + kb * 8;
            GLOBAL_TO_LDS16(ga, As + rbase * 64);
            const ushort* gb = B + (size_t)(bn + rbase + r8) * K + k0 + kb * 8;
            GLOBAL_TO_LDS16(gb, Bs + rbase * 64);
        }
        __syncthreads();                 // drains vmcnt before compute

#pragma unroll
        for (int ks = 0; ks < 2; ks++) {
            bf16x8 af[4], bfr[4];
            int kblk = ks * 4 + quad;
#pragma unroll
            for (int mi = 0; mi < 4; mi++) {
                int row = wr + mi * 16 + n;
                af[mi] = *(const bf16x8*)(As + (row * 8 + (kblk ^ (row & 7))) * 8);
            }
#pragma unroll
            for (int ni = 0; ni < 4; ni++) {
                int row = wc + ni * 16 + n;
                bfr[ni] = *(const bf16x8*)(Bs + (row * 8 + (kblk ^ (row & 7))) * 8);
            }
#pragma unroll
            for (int mi = 0; mi < 4; mi++)
#pragma unroll
                for (int ni = 0; ni < 4; ni++)
                    acc[mi][ni] = __builtin_amdgcn_mfma_f32_16x16x32_bf16(
                        af[mi], bfr[ni], acc[mi][ni], 0, 0, 0);
        }
    }

#pragma unroll
    for (int mi = 0; mi < 4; mi++)
#pragma unroll
        for (int ni = 0; ni < 4; ni++)
#pragma unroll
            for (int r = 0; r < 4; r++) {
                int row = bm + wr + mi * 16 + quad * 4 + r;
                int col = bn + wc + ni * 16 + n;
                size_t idx = (size_t)row * N + col;
                float v = acc[mi][ni][r];
                if (EPILOGUE) OUT[idx] = X[idx] + v;
                else          C[idx]   = v;
            }
}

// ------------- pack_qk: fused RoPE + bf16 cast + per-head layout ---------
__global__ void pack_qk_kernel(const float* __restrict__ qkv,
                               __hip_bfloat16* __restrict__ Qb,
                               __hip_bfloat16* __restrict__ Kb) {
    int t = blockIdx.x;
    int b = t >> 11, s = t & (SEQ - 1);
    const float* row = qkv + (size_t)t * CONCAT;
    const float LOG2_THETA = 13.287712379549449f;
    for (int i = threadIdx.x; i < CQ + CK; i += 256) {
        int head, d;
        const float* hb;
        if (i < CQ) { head = i >> 6; d = i & 63; hb = row + head * 64; }
        else { head = (i - CQ) >> 6; d = (i - CQ) & 63; hb = row + CQ + head * 64; }
        int j = d & 31;
        float inv = exp2f(-((float)j / 32.0f) * LOG2_THETA);
        float ang = (float)s * inv;
        float c = cosf(ang), sn = sinf(ang);
        float val;
        if (d < 32) val = hb[d] * c - hb[d + 32] * sn;
        else        val = hb[d] * c + hb[d - 32] * sn;
        __hip_bfloat16 bv = __float2bfloat16(val);
        if (i < CQ) {
            int g = head >> 2, h = head & 3;
            Qb[((size_t)((b * 8 + g) * 4 + h) * SEQ + s) * 64 + d] = bv;
        } else {
            Kb[((size_t)(b * 8 + head) * SEQ + s) * 64 + d] = bv;
        }
    }
}

// ------------- pack_v: transpose V to [b][g][d][s] bf16 via LDS ----------
__global__ void pack_v_kernel(const float* __restrict__ qkv,
                              __hip_bfloat16* __restrict__ Vb) {
    int st = blockIdx.x & 31, bg = blockIdx.x >> 5;
    int b = bg >> 3, g = bg & 7;
    __shared__ float tile[64][65];
    int tid = threadIdx.x;
    int ls = tid >> 6;
    int d = tid & 63;
#pragma unroll
    for (int i = 0; i < 16; i++) {
        int s = st * 64 + i * 4 + ls;
        tile[i * 4 + ls][d] = qkv[(size_t)(b * SEQ + s) * CONCAT + CQ + CK + g * 64 + d];
    }
    __syncthreads();
#pragma unroll
    for (int i = 0; i < 16; i++) {
        int drow = i * 4 + ls;
        int scol = tid & 63;
        Vb[((size_t)(bg * 64 + drow)) * SEQ + st * 64 + scol] =
            __float2bfloat16(tile[scol][drow]);
    }
}

// ---------------- MFMA flash attention (bf16 O out) ----------------------
__global__ __launch_bounds__(256) void attn_mfma_kernel(
        const ushort* __restrict__ Qb, const ushort* __restrict__ Kb,
        const ushort* __restrict__ Vb, ushort* __restrict__ o_bf) {
    __shared__ __align__(16) ushort Kl[519 * 8];
    __shared__ __align__(16) ushort Vl[519 * 8];
    __shared__ __align__(16) ushort Pl[4][1024];

    int qt = blockIdx.x & 31;
    int bgh = blockIdx.x >> 5;
    int h = bgh & 3, g = (bgh >> 2) & 7, b = bgh >> 5;
    int w = threadIdx.x >> 6, lane = threadIdx.x & 63;
    int n = lane & 15, quad = lane >> 4;
    int qbase = qt * 64;

    const ushort* Qh = Qb + (size_t)((b * 8 + g) * 4 + h) * (SEQ * 64);
    const ushort* Kg0 = Kb + (size_t)(b * 8 + g) * (SEQ * 64);
    const ushort* Vg0 = Vb + (size_t)(b * 8 + g) * (64 * SEQ);

    int qrow = qbase + w * 16 + n;
    bf16x8 aq0 = *(const bf16x8*)(Qh + (size_t)qrow * 64 + quad * 8);
    bf16x8 aq1 = *(const bf16x8*)(Qh + (size_t)qrow * 64 + 32 + quad * 8);

    f32x4 od[4] = {};
    float mrow[4], lrow[4];
#pragma unroll
    for (int r = 0; r < 4; r++) { mrow[r] = -1e30f; lrow[r] = 0.f; }

    ushort* Pw = Pl[w];
    int nkt = qt + 1;
    for (int kt = 0; kt < nkt; kt++) {
        __syncthreads();
        {
            const ushort* Kg = Kg0 + kt * 64 * 64;
            const ushort* Vg = Vg0 + kt * 64;
#pragma unroll
            for (int rep = 0; rep < 2; rep++) {
                int e = (rep * 256 + threadIdx.x) * 8;
                int key = e >> 6, dblk = (e >> 3) & 7;
                *(bf16x8*)(Kl + (dblk * 65 + key) * 8) = *(const bf16x8*)(Kg + e);
            }
#pragma unroll
            for (int rep = 0; rep < 2; rep++) {
                int e = (rep * 256 + threadIdx.x) * 8;
                int d = e >> 6, kin = e & 63;
                *(bf16x8*)(Vl + ((kin >> 3) * 65 + d) * 8) =
                    *(const bf16x8*)(Vg + (size_t)d * SEQ + kin);
            }
        }
        __syncthreads();

        bool diag = (kt == qt);
        f32x4 s4[4];
#pragma unroll
        for (int t16 = 0; t16 < 4; t16++) {
            if (diag && t16 > w) {
#pragma unroll
                for (int r = 0; r < 4; r++) s4[t16][r] = -1e30f;
                continue;
            }
            bf16x8 bk0 = *(const bf16x8*)(Kl + ((quad) * 65 + t16 * 16 + n) * 8);
            bf16x8 bk1 = *(const bf16x8*)(Kl + ((4 + quad) * 65 + t16 * 16 + n) * 8);
            f32x4 c = {};
            c = __builtin_amdgcn_mfma_f32_16x16x32_bf16(aq0, bk0, c, 0, 0, 0);
            c = __builtin_amdgcn_mfma_f32_16x16x32_bf16(aq1, bk1, c, 0, 0, 0);
#pragma unroll
            for (int r = 0; r < 4; r++) {
                float sv = c[r] * 0.125f;
                if (diag && t16 == w) {
                    int keyr = t16 * 16 + n;
                    int qr = w * 16 + quad * 4 + r;
                    if (keyr > qr) sv = -1e30f;
                }
                s4[t16][r] = sv;
            }
        }

        float rmax[4], alpha[4], rsum[4];
#pragma unroll
        for (int r = 0; r < 4; r++)
            rmax[r] = fmaxf(fmaxf(s4[0][r], s4[1][r]), fmaxf(s4[2][r], s4[3][r]));
#pragma unroll
        for (int off = 1; off < 16; off <<= 1)
#pragma unroll
            for (int r = 0; r < 4; r++)
                rmax[r] = fmaxf(rmax[r], __shfl_xor(rmax[r], off));
#pragma unroll
        for (int r = 0; r < 4; r++) {
            float mn = fmaxf(mrow[r], rmax[r]);
            alpha[r] = __expf(mrow[r] - mn);
            mrow[r] = mn;
            rsum[r] = 0.f;
        }
#pragma unroll
        for (int t16 = 0; t16 < 4; t16++)
#pragma unroll
            for (int r = 0; r < 4; r++) {
                float p = __expf(s4[t16][r] - mrow[r]);
                rsum[r] += p;
                int key = t16 * 16 + n;
                Pw[((key >> 3) * 16 + quad * 4 + r) * 8 + (key & 7)] = f2bf(p);
            }
#pragma unroll
        for (int off = 1; off < 16; off <<= 1)
#pragma unroll
            for (int r = 0; r < 4; r++) rsum[r] += __shfl_xor(rsum[r], off);
#pragma unroll
        for (int r = 0; r < 4; r++) lrow[r] = lrow[r] * alpha[r] + rsum[r];
#pragma unroll
        for (int dt = 0; dt < 4; dt++)
#pragma unroll
            for (int r = 0; r < 4; r++) od[dt][r] *= alpha[r];

#pragma unroll
        for (int kb = 0; kb < 2; kb++) {
            bf16x8 ap = *(const bf16x8*)(Pw + ((kb * 4 + quad) * 16 + n) * 8);
#pragma unroll
            for (int dt = 0; dt < 4; dt++) {
                bf16x8 bv = *(const bf16x8*)(Vl + ((kb * 4 + quad) * 65 + dt * 16 + n) * 8);
                od[dt] = __builtin_amdgcn_mfma_f32_16x16x32_bf16(ap, bv, od[dt], 0, 0, 0);
            }
        }
    }

#pragma unroll
    for (int dt = 0; dt < 4; dt++)
#pragma unroll
        for (int r = 0; r < 4; r++) {
            int q = qbase + w * 16 + quad * 4 + r;
            int col = (g * 4 + h) * 64 + dt * 16 + n;
            o_bf[(size_t)(b * SEQ + q) * DMODEL + col] = f2bf(od[dt][r] / lrow[r]);
        }
}

extern "C" void kernel_launch(void* const* d_in, const int* in_sizes, int n_in,
                              void* d_out, int out_size, void* d_ws, size_t ws_size,
                              hipStream_t stream) {
    const float* x     = (const float*)d_in[0];
    const float* w_in  = (const float*)d_in[1];
    const float* w_out = (const float*)d_in[2];
    const float* rms_w = (const float*)d_in[3];
    float* out = (float*)d_out;

    // Workspace layout with liveness overlap (peak 76 MB):
    //   [0,48)MB  qkv f32           -> after packs: o_bf [0,16), w_out_bf [16,24)
    //   [48,64)MB y_bf              -> after GEMM-in: Qb
    //   [64,76)MB w_in_bf           -> after GEMM-in: Kb [64,68), Vb [68,72)
    const size_t MB = 1024 * 1024;
    char* ws = (char*)d_ws;
    float*  qkv      = (float*)ws;
    ushort* y_bf     = (ushort*)(ws + 48 * MB);
    ushort* w_in_bf  = (ushort*)(ws + 64 * MB);
    ushort* Qb       = (ushort*)(ws + 48 * MB);
    ushort* Kb       = (ushort*)(ws + 64 * MB);
    ushort* Vb       = (ushort*)(ws + 68 * MB);
    ushort* o_bf     = (ushort*)ws;
    ushort* w_out_bf = (ushort*)(ws + 16 * MB);

    rmsnorm_kernel<<<TOKENS, 256, 0, stream>>>(x, rms_w, y_bf);
    pack_bf16_kernel<<<(CONCAT * DMODEL / 4 + 255) / 256, 256, 0, stream>>>(
        w_in, w_in_bf, CONCAT * DMODEL / 4);

    gemm_nt_mfma<false><<<dim3(CONCAT / 128, TOKENS / 128), 256, 0, stream>>>(
        y_bf, w_in_bf, qkv, nullptr, nullptr, TOKENS, CONCAT, DMODEL);

    pack_qk_kernel<<<TOKENS, 256, 0, stream>>>(qkv, (__hip_bfloat16*)Qb,
                                               (__hip_bfloat16*)Kb);
    pack_v_kernel<<<512, 256, 0, stream>>>(qkv, (__hip_bfloat16*)Vb);
    pack_bf16_kernel<<<(DMODEL * DMODEL / 4 + 255) / 256, 256, 0, stream>>>(
        w_out, w_out_bf, DMODEL * DMODEL / 4);

    attn_mfma_kernel<<<2048, 256, 0, stream>>>(Qb, Kb, Vb, o_bf);

    gemm_nt_mfma<true><<<dim3(DMODEL / 128, TOKENS / 128), 256, 0, stream>>>(
        o_bf, w_out_bf, nullptr, x, out, TOKENS, DMODEL, DMODEL);
}

// Round 5
// 331.660 us; speedup vs baseline: 32.3515x; 1.4565x over previous
//
#include <hip/hip_runtime.h>
#include <hip/hip_bf16.h>

// fp32 problem: b=2, s=2048, D=2048, 32 q-heads / 8 kv-groups, d=64
#define TOKENS   4096
#define SEQ      2048
#define DMODEL   2048
#define CONCAT   3072
#define NHEADS   32
#define NGROUPS  8
#define HPERG    4
#define CQ       2048
#define CK       512

typedef __attribute__((ext_vector_type(8))) short bf16x8;
typedef __attribute__((ext_vector_type(4))) float f32x4;

__device__ __forceinline__ ushort f2bf(float f) {
    __hip_bfloat16 h = __float2bfloat16(f);
    return __builtin_bit_cast(ushort, h);
}

#define GLOBAL_TO_LDS16(g, l)                                                  \
    __builtin_amdgcn_global_load_lds(                                          \
        (const __attribute__((address_space(1))) void*)(g),                    \
        (__attribute__((address_space(3))) void*)(l), 16, 0, 0)

// ---------------- RMSNorm: one block (256 thr) per token, bf16 out -------
__global__ void rmsnorm_kernel(const float* __restrict__ x,
                               const float* __restrict__ w,
                               ushort* __restrict__ y_bf) {
    int t = blockIdx.x;
    const float4* xr = (const float4*)(x + (size_t)t * DMODEL);
    float4 v[2];
    float ss = 0.f;
#pragma unroll
    for (int i = 0; i < 2; i++) {
        v[i] = xr[threadIdx.x + i * 256];
        ss += v[i].x * v[i].x + v[i].y * v[i].y + v[i].z * v[i].z + v[i].w * v[i].w;
    }
#pragma unroll
    for (int off = 32; off >= 1; off >>= 1) ss += __shfl_xor(ss, off);
    __shared__ float red[4];
    int wid = threadIdx.x >> 6;
    if ((threadIdx.x & 63) == 0) red[wid] = ss;
    __syncthreads();
    float total = red[0] + red[1] + red[2] + red[3];
    float scale = rsqrtf(total * (1.0f / DMODEL) + 1e-6f);
    const float4* wr = (const float4*)w;
    ushort4* yr = (ushort4*)(y_bf + (size_t)t * DMODEL);
#pragma unroll
    for (int i = 0; i < 2; i++) {
        int c = threadIdx.x + i * 256;
        float4 wv = wr[c];
        ushort4 o;
        o.x = f2bf(v[i].x * scale * wv.x);
        o.y = f2bf(v[i].y * scale * wv.y);
        o.z = f2bf(v[i].z * scale * wv.z);
        o.w = f2bf(v[i].w * scale * wv.w);
        yr[c] = o;
    }
}

// ---------------- fp32 -> bf16 cast (weights) ----------------------------
__global__ void pack_bf16_kernel(const float* __restrict__ src,
                                 ushort* __restrict__ dst, int n4) {
    int i = blockIdx.x * 256 + threadIdx.x;
    if (i < n4) {
        float4 v = ((const float4*)src)[i];
        ushort4 o;
        o.x = f2bf(v.x); o.y = f2bf(v.y); o.z = f2bf(v.z); o.w = f2bf(v.w);
        ((ushort4*)dst)[i] = o;
    }
}

// ---------------- MFMA GEMM: C[M,N] = A[M,K] * B[N,K]^T (bf16 in) --------
template <bool EPILOGUE>
__global__ __launch_bounds__(256) void gemm_nt_mfma(
        const ushort* __restrict__ A, const ushort* __restrict__ B,
        float* __restrict__ C, const float* __restrict__ X,
        float* __restrict__ OUT, int M, int N, int K) {
    __shared__ __align__(16) ushort As[128 * 64];
    __shared__ __align__(16) ushort Bs[128 * 64];

    const int bm = blockIdx.y * 128, bn = blockIdx.x * 128;
    const int w = threadIdx.x >> 6, lane = threadIdx.x & 63;
    const int n = lane & 15, quad = lane >> 4;
    const int wr = (w & 1) * 64, wc = (w >> 1) * 64;

    const int r8 = lane >> 3;
    const int kb = (lane & 7) ^ r8;

    f32x4 acc[4][4] = {};

    for (int k0 = 0; k0 < K; k0 += 64) {
        __syncthreads();
#pragma unroll
        for (int i = 0; i < 4; i++) {
            int rbase = (w * 4 + i) * 8;
            const ushort* ga = A + (size_t)(bm + rbase + r8) * K + k0 + kb * 8;
            GLOBAL_TO_LDS16(ga, As + rbase * 64);
            const ushort* gb = B + (size_t)(bn + rbase + r8) * K + k0 + kb * 8;
            GLOBAL_TO_LDS16(gb, Bs + rbase * 64);
        }
        __syncthreads();

#pragma unroll
        for (int ks = 0; ks < 2; ks++) {
            bf16x8 af[4], bfr[4];
            int kblk = ks * 4 + quad;
#pragma unroll
            for (int mi = 0; mi < 4; mi++) {
                int row = wr + mi * 16 + n;
                af[mi] = *(const bf16x8*)(As + (row * 8 + (kblk ^ (row & 7))) * 8);
            }
#pragma unroll
            for (int ni = 0; ni < 4; ni++) {
                int row = wc + ni * 16 + n;
                bfr[ni] = *(const bf16x8*)(Bs + (row * 8 + (kblk ^ (row & 7))) * 8);
            }
#pragma unroll
            for (int mi = 0; mi < 4; mi++)
#pragma unroll
                for (int ni = 0; ni < 4; ni++)
                    acc[mi][ni] = __builtin_amdgcn_mfma_f32_16x16x32_bf16(
                        af[mi], bfr[ni], acc[mi][ni], 0, 0, 0);
        }
    }

#pragma unroll
    for (int mi = 0; mi < 4; mi++)
#pragma unroll
        for (int ni = 0; ni < 4; ni++)
#pragma unroll
            for (int r = 0; r < 4; r++) {
                int row = bm + wr + mi * 16 + quad * 4 + r;
                int col = bn + wc + ni * 16 + n;
                size_t idx = (size_t)row * N + col;
                float v = acc[mi][ni][r];
                if (EPILOGUE) OUT[idx] = X[idx] + v;
                else          C[idx]   = v;
            }
}

// ------------- pack_qk: fused RoPE + bf16 cast + per-head layout ---------
// Q additionally pre-scaled by 0.125*log2(e) so QK^T MFMA output is the
// log2-domain score directly (no-max exp2 softmax in attention).
__global__ void pack_qk_kernel(const float* __restrict__ qkv,
                               __hip_bfloat16* __restrict__ Qb,
                               __hip_bfloat16* __restrict__ Kb) {
    int t = blockIdx.x;
    int b = t >> 11, s = t & (SEQ - 1);
    const float* row = qkv + (size_t)t * CONCAT;
    const float LOG2_THETA = 13.287712379549449f;
    const float QSCALE = 0.18033688011112042f;  // 0.125 * log2(e)
    for (int i = threadIdx.x; i < CQ + CK; i += 256) {
        int head, d;
        const float* hb;
        if (i < CQ) { head = i >> 6; d = i & 63; hb = row + head * 64; }
        else { head = (i - CQ) >> 6; d = (i - CQ) & 63; hb = row + CQ + head * 64; }
        int j = d & 31;
        float inv = exp2f(-((float)j / 32.0f) * LOG2_THETA);
        float ang = (float)s * inv;
        float c = cosf(ang), sn = sinf(ang);
        float val;
        if (d < 32) val = hb[d] * c - hb[d + 32] * sn;
        else        val = hb[d] * c + hb[d - 32] * sn;
        if (i < CQ) val *= QSCALE;
        __hip_bfloat16 bv = __float2bfloat16(val);
        if (i < CQ) {
            int g = head >> 2, h = head & 3;
            Qb[((size_t)((b * 8 + g) * 4 + h) * SEQ + s) * 64 + d] = bv;
        } else {
            Kb[((size_t)(b * 8 + head) * SEQ + s) * 64 + d] = bv;
        }
    }
}

// ------------- pack_v: transpose V to [b][g][d][s] bf16 via LDS ----------
__global__ void pack_v_kernel(const float* __restrict__ qkv,
                              __hip_bfloat16* __restrict__ Vb) {
    int st = blockIdx.x & 31, bg = blockIdx.x >> 5;
    int b = bg >> 3, g = bg & 7;
    __shared__ float tile[64][65];
    int tid = threadIdx.x;
    int ls = tid >> 6;
    int d = tid & 63;
#pragma unroll
    for (int i = 0; i < 16; i++) {
        int s = st * 64 + i * 4 + ls;
        tile[i * 4 + ls][d] = qkv[(size_t)(b * SEQ + s) * CONCAT + CQ + CK + g * 64 + d];
    }
    __syncthreads();
#pragma unroll
    for (int i = 0; i < 16; i++) {
        int drow = i * 4 + ls;
        int scol = tid & 63;
        Vb[((size_t)(bg * 64 + drow)) * SEQ + st * 64 + scol] =
            __float2bfloat16(tile[scol][drow]);
    }
}

// ---------------- MFMA flash attention, v2 -------------------------------
// Block = (b,g,h, 128-query tile); 4 waves x 32 query rows (2 groups of 16).
// No-max exp2 softmax (Q pre-scaled): p = v_exp(S2), l = ones-column MFMA.
// S^T via operand swap -> consecutive keys in-lane -> packed-dword P writes.
// LDS layouts:
//   Kl[(dblk*65 + key)*8 + (d&7)]         (K tile, A-operand frag order)
//   Vl[(key>>3)*65 + d]*8 + (key&7)       (V tile, B-operand frag order)
//   Pl[w] dwords: ((key>>3)*33 + q)*4 + ((key&7)>>1)  (A-operand, q in [0,32))
__global__ __launch_bounds__(256) void attn_mfma_kernel(
        const ushort* __restrict__ Qb, const ushort* __restrict__ Kb,
        const ushort* __restrict__ Vb, ushort* __restrict__ o_bf) {
    __shared__ __align__(16) ushort Kl[519 * 8];
    __shared__ __align__(16) ushort Vl[519 * 8];
    __shared__ __align__(16) uint   Pl[4][1056];

    int blk = blockIdx.x;
    int qt  = 15 - (blk >> 6);          // longest blocks dispatch first
    int bgh = blk & 63;
    int h = bgh & 3, g = (bgh >> 2) & 7, b = bgh >> 5;
    int w = threadIdx.x >> 6, lane = threadIdx.x & 63;
    int n = lane & 15, quad = lane >> 4;
    int Q0 = qt * 128;
    int qw = Q0 + w * 32;               // wave's first query row

    const ushort* Qh  = Qb + (size_t)((b * 8 + g) * 4 + h) * (SEQ * 64);
    const ushort* Kg0 = Kb + (size_t)(b * 8 + g) * (SEQ * 64);
    const ushort* Vg0 = Vb + (size_t)(b * 8 + g) * (64 * SEQ);

    // Q fragments (rows of Q; identical per-lane data for A- or B-operand use)
    bf16x8 aq[2][2];
#pragma unroll
    for (int qg = 0; qg < 2; qg++)
#pragma unroll
        for (int ks = 0; ks < 2; ks++)
            aq[qg][ks] = *(const bf16x8*)(
                Qh + (size_t)(qw + qg * 16 + n) * 64 + ks * 32 + quad * 8);

    f32x4 od[2][4] = {};
    f32x4 od4[2] = {};

    short onev = (n == 0) ? (short)0x3F80 : (short)0;
    bf16x8 bones = {onev, onev, onev, onev, onev, onev, onev, onev};

    uint* Pw = Pl[w];
    int nkt = qt * 2 + 2;
    for (int kt = 0; kt < nkt; kt++) {
        __syncthreads();                 // previous iteration's readers done
        {
            const ushort* Kg = Kg0 + kt * 64 * 64;
            const ushort* Vg = Vg0 + kt * 64;
#pragma unroll
            for (int rep = 0; rep < 2; rep++) {
                int e = (rep * 256 + threadIdx.x) * 8;
                int key = e >> 6, dblk = (e >> 3) & 7;
                *(bf16x8*)(Kl + (dblk * 65 + key) * 8) = *(const bf16x8*)(Kg + e);
            }
#pragma unroll
            for (int rep = 0; rep < 2; rep++) {
                int e = (rep * 256 + threadIdx.x) * 8;
                int d = e >> 6, kin = e & 63;
                *(bf16x8*)(Vl + ((kin >> 3) * 65 + d) * 8) =
                    *(const bf16x8*)(Vg + (size_t)d * SEQ + kin);
            }
        }
        __syncthreads();

        bool act1 = (kt * 64 <= qw + 31);   // any of this wave's rows see kt?
        if (!act1) continue;                // (loops back to the barrier)
        bool act0 = (kt * 64 <= qw + 15);

        // S^T = K Q^T (operand swap), exp2, pack, P write
#pragma unroll
        for (int t16k = 0; t16k < 4; t16k++) {
            bf16x8 kf0 = *(const bf16x8*)(Kl + ((0 + quad) * 65 + t16k * 16 + n) * 8);
            bf16x8 kf1 = *(const bf16x8*)(Kl + ((4 + quad) * 65 + t16k * 16 + n) * 8);
            int key0 = kt * 64 + t16k * 16 + quad * 4;
#pragma unroll
            for (int qg = 0; qg < 2; qg++) {
                if (qg == 0 && !act0) continue;
                f32x4 c = {};
                c = __builtin_amdgcn_mfma_f32_16x16x32_bf16(kf0, aq[qg][0], c, 0, 0, 0);
                c = __builtin_amdgcn_mfma_f32_16x16x32_bf16(kf1, aq[qg][1], c, 0, 0, 0);
                int qrow = qw + qg * 16 + n;
                float p[4];
                if (kt * 64 + 63 > qw + qg * 16) {   // tile may mask
#pragma unroll
                    for (int r = 0; r < 4; r++)
                        p[r] = (key0 + r <= qrow) ? __builtin_amdgcn_exp2f(c[r]) : 0.f;
                } else {
#pragma unroll
                    for (int r = 0; r < 4; r++)
                        p[r] = __builtin_amdgcn_exp2f(c[r]);
                }
                uint d0 = ((uint)f2bf(p[1]) << 16) | f2bf(p[0]);
                uint d1 = ((uint)f2bf(p[3]) << 16) | f2bf(p[2]);
                int base = ((t16k * 2 + (quad >> 1)) * 33 + qg * 16 + n) * 4
                           + (quad & 1) * 2;
                Pw[base]     = d0;
                Pw[base + 1] = d1;
            }
        }

        // O += P V   (+ ones column accumulates l)
#pragma unroll
        for (int kb2 = 0; kb2 < 2; kb2++) {
            bf16x8 bv[4];
#pragma unroll
            for (int dt = 0; dt < 4; dt++)
                bv[dt] = *(const bf16x8*)(Vl + ((kb2 * 4 + quad) * 65 + dt * 16 + n) * 8);
#pragma unroll
            for (int qg = 0; qg < 2; qg++) {
                if (qg == 0 && !act0) continue;
                bf16x8 ap = *(const bf16x8*)(
                    (const ushort*)Pw + ((kb2 * 4 + quad) * 33 + qg * 16 + n) * 8);
#pragma unroll
                for (int dt = 0; dt < 4; dt++)
                    od[qg][dt] = __builtin_amdgcn_mfma_f32_16x16x32_bf16(
                        ap, bv[dt], od[qg][dt], 0, 0, 0);
                od4[qg] = __builtin_amdgcn_mfma_f32_16x16x32_bf16(
                    ap, bones, od4[qg], 0, 0, 0);
            }
        }
    }

    // epilogue: l lives in column 0 of od4 (lane n==0); broadcast, divide
#pragma unroll
    for (int qg = 0; qg < 2; qg++) {
        float linv[4];
#pragma unroll
        for (int r = 0; r < 4; r++) {
            float lv = __shfl(od4[qg][r], lane & 48);
            linv[r] = __builtin_amdgcn_rcpf(lv);
        }
#pragma unroll
        for (int dt = 0; dt < 4; dt++)
#pragma unroll
            for (int r = 0; r < 4; r++) {
                int q = qw + qg * 16 + quad * 4 + r;
                int col = (g * 4 + h) * 64 + dt * 16 + n;
                o_bf[(size_t)(b * SEQ + q) * DMODEL + col] =
                    f2bf(od[qg][dt][r] * linv[r]);
            }
    }
}

extern "C" void kernel_launch(void* const* d_in, const int* in_sizes, int n_in,
                              void* d_out, int out_size, void* d_ws, size_t ws_size,
                              hipStream_t stream) {
    const float* x     = (const float*)d_in[0];
    const float* w_in  = (const float*)d_in[1];
    const float* w_out = (const float*)d_in[2];
    const float* rms_w = (const float*)d_in[3];
    float* out = (float*)d_out;

    // Workspace layout with liveness overlap (peak 76 MB):
    //   [0,48)MB  qkv f32           -> after packs: o_bf [0,16), w_out_bf [16,24)
    //   [48,64)MB y_bf              -> after GEMM-in: Qb
    //   [64,76)MB w_in_bf           -> after GEMM-in: Kb [64,68), Vb [68,72)
    const size_t MB = 1024 * 1024;
    char* ws = (char*)d_ws;
    float*  qkv      = (float*)ws;
    ushort* y_bf     = (ushort*)(ws + 48 * MB);
    ushort* w_in_bf  = (ushort*)(ws + 64 * MB);
    ushort* Qb       = (ushort*)(ws + 48 * MB);
    ushort* Kb       = (ushort*)(ws + 64 * MB);
    ushort* Vb       = (ushort*)(ws + 68 * MB);
    ushort* o_bf     = (ushort*)ws;
    ushort* w_out_bf = (ushort*)(ws + 16 * MB);

    rmsnorm_kernel<<<TOKENS, 256, 0, stream>>>(x, rms_w, y_bf);
    pack_bf16_kernel<<<(CONCAT * DMODEL / 4 + 255) / 256, 256, 0, stream>>>(
        w_in, w_in_bf, CONCAT * DMODEL / 4);

    gemm_nt_mfma<false><<<dim3(CONCAT / 128, TOKENS / 128), 256, 0, stream>>>(
        y_bf, w_in_bf, qkv, nullptr, nullptr, TOKENS, CONCAT, DMODEL);

    pack_qk_kernel<<<TOKENS, 256, 0, stream>>>(qkv, (__hip_bfloat16*)Qb,
                                               (__hip_bfloat16*)Kb);
    pack_v_kernel<<<512, 256, 0, stream>>>(qkv, (__hip_bfloat16*)Vb);
    pack_bf16_kernel<<<(DMODEL * DMODEL / 4 + 255) / 256, 256, 0, stream>>>(
        w_out, w_out_bf, DMODEL * DMODEL / 4);

    attn_mfma_kernel<<<1024, 256, 0, stream>>>(Qb, Kb, Vb, o_bf);

    gemm_nt_mfma<true><<<dim3(DMODEL / 128, TOKENS / 128), 256, 0, stream>>>(
        o_bf, w_out_bf, nullptr, x, out, TOKENS, DMODEL, DMODEL);
}